// Round 1
// baseline (351.430 us; speedup 1.0000x reference)
//
#include <hip/hip_runtime.h>
#include <hip/hip_bf16.h>
#include <math.h>

#define N_NODES 50000
#define N_EDGES 400000
#define IN_DIM 256
#define OUT_DIM 64
#define HEADS 2
#define ATTN_HIDDEN 64
#define ALPHA_SLOPE 0.2f
#define TEMP 0.55f
#define NHF 128  // HEADS*OUT_DIM

// ---------------------------------------------------------------------------
// K1: Wh[n, h*64+f] = sum_d x[n,d] * W[d, h*64+f]
// [50000,256] x [256,128] fp32 GEMM. Tile 64 rows x 128 cols per 256-thread
// block; each thread computes 4x8 outputs. K-chunk 16.
// ---------------------------------------------------------------------------
__global__ __launch_bounds__(256) void k_proj(const float* __restrict__ x,
                                              const float* __restrict__ W,
                                              float* __restrict__ Wh) {
    __shared__ float xs[64][17];   // pad 17 to break 4-way bank conflict
    __shared__ float ws[16][128];
    const int tid = threadIdx.x;
    const int tx = tid & 15;       // col group -> cols 8*tx..8*tx+7
    const int ty = tid >> 4;       // row group -> rows 4*ty..4*ty+3
    const int row0 = blockIdx.x * 64;

    float acc[4][8];
#pragma unroll
    for (int i = 0; i < 4; i++)
#pragma unroll
        for (int j = 0; j < 8; j++) acc[i][j] = 0.f;

    for (int k0 = 0; k0 < IN_DIM; k0 += 16) {
        // stage x tile: 64 rows x 16 k
        {
            int r = tid >> 2;
            int kq = (tid & 3) * 4;
            int gr = row0 + r;
            float4 v = make_float4(0.f, 0.f, 0.f, 0.f);
            if (gr < N_NODES) v = *(const float4*)&x[(size_t)gr * IN_DIM + k0 + kq];
            xs[r][kq + 0] = v.x; xs[r][kq + 1] = v.y;
            xs[r][kq + 2] = v.z; xs[r][kq + 3] = v.w;
        }
        // stage W tile: 16 k x 128 cols
        {
            int kr = tid >> 4;
            int cq = (tid & 15) * 8;
            const float* wp = &W[(size_t)(k0 + kr) * NHF + cq];
            *(float4*)&ws[kr][cq]     = *(const float4*)&wp[0];
            *(float4*)&ws[kr][cq + 4] = *(const float4*)&wp[4];
        }
        __syncthreads();
#pragma unroll
        for (int kk = 0; kk < 16; kk++) {
            float a[4], b[8];
#pragma unroll
            for (int i = 0; i < 4; i++) a[i] = xs[4 * ty + i][kk];
#pragma unroll
            for (int j = 0; j < 8; j++) b[j] = ws[kk][8 * tx + j];
#pragma unroll
            for (int i = 0; i < 4; i++)
#pragma unroll
                for (int j = 0; j < 8; j++) acc[i][j] += a[i] * b[j];
        }
        __syncthreads();
    }
#pragma unroll
    for (int i = 0; i < 4; i++) {
        int gr = row0 + 4 * ty + i;
        if (gr < N_NODES) {
            float* op = &Wh[(size_t)gr * NHF + 8 * tx];
            *(float4*)&op[0] = make_float4(acc[i][0], acc[i][1], acc[i][2], acc[i][3]);
            *(float4*)&op[4] = make_float4(acc[i][4], acc[i][5], acc[i][6], acc[i][7]);
        }
    }
}

// ---------------------------------------------------------------------------
// K2: U_s[n,h,c] = sum_f Wh[n,h,f]*Wa[h,f,c];  U_d uses Wa[h,64+f,c].
// Full W_attn (64KB) in LDS; each block handles 16 nodes (4 waves x 4 nodes,
// lane = c). Wh rows staged in LDS, broadcast-read.
// Grid must be exactly 50000/16 = 3125.
// ---------------------------------------------------------------------------
__global__ __launch_bounds__(256) void k_uprep(const float* __restrict__ Wh,
                                               const float* __restrict__ Wa,
                                               float* __restrict__ Us,
                                               float* __restrict__ Ud) {
    __shared__ float waL[HEADS * 2 * OUT_DIM * ATTN_HIDDEN];  // 16384 floats
    __shared__ float whL[16 * NHF];                           // 2048 floats
    const int tid = threadIdx.x;
    for (int i = tid * 4; i < 16384; i += 1024)
        *(float4*)&waL[i] = *(const float4*)&Wa[i];
    const int n0 = blockIdx.x * 16;
    *(float4*)&whL[tid * 4]        = *(const float4*)&Wh[(size_t)n0 * NHF + tid * 4];
    *(float4*)&whL[tid * 4 + 1024] = *(const float4*)&Wh[(size_t)n0 * NHF + tid * 4 + 1024];
    __syncthreads();

    const int wave = tid >> 6;
    const int c = tid & 63;
    float acc_s[2][4], acc_d[2][4];
#pragma unroll
    for (int h = 0; h < 2; h++)
#pragma unroll
        for (int p = 0; p < 4; p++) { acc_s[h][p] = 0.f; acc_d[h][p] = 0.f; }

#pragma unroll
    for (int h = 0; h < 2; h++) {
        for (int f = 0; f < 64; f++) {
            float was = waL[h * 8192 + f * 64 + c];
            float wad = waL[h * 8192 + (64 + f) * 64 + c];
#pragma unroll
            for (int p = 0; p < 4; p++) {
                float wh = whL[(wave * 4 + p) * NHF + h * 64 + f];
                acc_s[h][p] += wh * was;
                acc_d[h][p] += wh * wad;
            }
        }
    }
#pragma unroll
    for (int p = 0; p < 4; p++) {
        int n = n0 + wave * 4 + p;
#pragma unroll
        for (int h = 0; h < 2; h++) {
            Us[(size_t)n * NHF + h * 64 + c] = acc_s[h][p];
            Ud[(size_t)n * NHF + h * 64 + c] = acc_d[h][p];
        }
    }
}

// ---------------------------------------------------------------------------
// K3: seg[n] = lower_bound(dst, n) for n in [0, N_NODES]; dst sorted.
// ---------------------------------------------------------------------------
__global__ void k_segstart(const int* __restrict__ dst, int* __restrict__ seg) {
    int n = blockIdx.x * blockDim.x + threadIdx.x;
    if (n > N_NODES) return;
    int lo = 0, hi = N_EDGES;
    while (lo < hi) {
        int mid = (lo + hi) >> 1;
        if (dst[mid] < n) lo = mid + 1; else hi = mid;
    }
    seg[n] = lo;
}

// ---------------------------------------------------------------------------
// K4: logits[e,h] = dot(a[h], lrelu(U_s[src[e],h,:] + U_d[dst[e],h,:])) / TEMP
// One wave per edge, lane = channel c, shuffle reduce.
// ---------------------------------------------------------------------------
__global__ __launch_bounds__(256) void k_logits(const float* __restrict__ Us,
                                                const float* __restrict__ Ud,
                                                const float* __restrict__ avec,
                                                const int* __restrict__ src,
                                                const int* __restrict__ dst,
                                                float* __restrict__ logits) {
    const int wave = threadIdx.x >> 6;
    const int c = threadIdx.x & 63;
    const int e = blockIdx.x * 4 + wave;
    if (e >= N_EDGES) return;
    const int s = src[e];
    const int d = dst[e];
#pragma unroll
    for (int h = 0; h < 2; h++) {
        float v = Us[(size_t)s * NHF + h * 64 + c] + Ud[(size_t)d * NHF + h * 64 + c];
        v = v > 0.f ? v : ALPHA_SLOPE * v;
        v *= avec[h * 64 + c];
#pragma unroll
        for (int off = 32; off > 0; off >>= 1) v += __shfl_xor(v, off, 64);
        if (c == 0) logits[(size_t)e * 2 + h] = v * (1.0f / TEMP);
    }
}

// ---------------------------------------------------------------------------
// K5: per-(node,head) segment softmax over sorted-dst edge ranges. In-place
// (alphas aliases logits; each thread owns its whole segment).
// ---------------------------------------------------------------------------
__global__ void k_softmax(const float* __restrict__ logits,
                          const int* __restrict__ seg,
                          float* __restrict__ alphas) {
    int t = blockIdx.x * blockDim.x + threadIdx.x;
    if (t >= N_NODES * 2) return;
    const int n = t >> 1;
    const int h = t & 1;
    const int e0 = seg[n], e1 = seg[n + 1];
    if (e0 >= e1) return;
    float m = -INFINITY;
    for (int e = e0; e < e1; e++) m = fmaxf(m, logits[(size_t)e * 2 + h]);
    float ssum = 0.f;
    for (int e = e0; e < e1; e++) ssum += expf(logits[(size_t)e * 2 + h] - m);
    const float inv = 1.f / (ssum + 1e-9f);
    for (int e = e0; e < e1; e++)
        alphas[(size_t)e * 2 + h] = expf(logits[(size_t)e * 2 + h] - m) * inv;
}

// ---------------------------------------------------------------------------
// K6: out[n,f] = 0.5 * sum_h sum_{e in seg(n)} alpha[e,h] * Wh[src[e],h,f]
// One wave per node, lane = f.
// ---------------------------------------------------------------------------
__global__ __launch_bounds__(256) void k_out(const float* __restrict__ Wh,
                                             const float* __restrict__ alphas,
                                             const int* __restrict__ src,
                                             const int* __restrict__ seg,
                                             float* __restrict__ out) {
    const int wave = threadIdx.x >> 6;
    const int f = threadIdx.x & 63;
    const int n = blockIdx.x * 4 + wave;
    if (n >= N_NODES) return;
    const int e0 = seg[n], e1 = seg[n + 1];
    float acc0 = 0.f, acc1 = 0.f;
    for (int e = e0; e < e1; e++) {
        const int s = src[e];
        const float a0 = alphas[(size_t)e * 2];
        const float a1 = alphas[(size_t)e * 2 + 1];
        acc0 += a0 * Wh[(size_t)s * NHF + f];
        acc1 += a1 * Wh[(size_t)s * NHF + 64 + f];
    }
    out[(size_t)n * 64 + f] = 0.5f * (acc0 + acc1);
}

// ---------------------------------------------------------------------------
extern "C" void kernel_launch(void* const* d_in, const int* in_sizes, int n_in,
                              void* d_out, int out_size, void* d_ws, size_t ws_size,
                              hipStream_t stream) {
    const float* x    = (const float*)d_in[0];
    const float* W    = (const float*)d_in[1];
    const float* Wa   = (const float*)d_in[2];
    const float* avec = (const float*)d_in[3];
    const int*   src  = (const int*)d_in[4];
    const int*   dst  = (const int*)d_in[5];
    float* out = (float*)d_out;

    float* ws = (float*)d_ws;
    float* Wh     = ws;                  //  6,400,000 floats
    float* Us     = ws + 6400000;        //  6,400,000
    float* Ud     = ws + 12800000;       //  6,400,000
    float* logits = ws + 19200000;       //    800,000 (reused in-place as alphas)
    int*   seg    = (int*)(ws + 20000000);  // 50,001 ints
    // total ~80.2 MB of workspace

    k_proj   <<<(N_NODES + 63) / 64, 256, 0, stream>>>(x, W, Wh);
    k_uprep  <<<N_NODES / 16, 256, 0, stream>>>(Wh, Wa, Us, Ud);
    k_segstart<<<(N_NODES + 1 + 255) / 256, 256, 0, stream>>>(dst, seg);
    k_logits <<<(N_EDGES + 3) / 4, 256, 0, stream>>>(Us, Ud, avec, src, dst, logits);
    k_softmax<<<(N_NODES * 2 + 255) / 256, 256, 0, stream>>>(logits, seg, logits);
    k_out    <<<(N_NODES + 3) / 4, 256, 0, stream>>>(Wh, logits, src, seg, out);
}

// Round 3
// 213.667 us; speedup vs baseline: 1.6448x; 1.6448x over previous
//
#include <hip/hip_runtime.h>
#include <hip/hip_bf16.h>
#include <math.h>

#define N_NODES 50000
#define N_EDGES 400000
#define IN_DIM 256
#define OUT_DIM 64
#define HEADS 2
#define ATTN_HIDDEN 64
#define ALPHA_SLOPE 0.2f
#define TEMP 0.55f
#define NHF 128   // HEADS*OUT_DIM
#define ZDIM 384  // Wh(128) | Us(128) | Ud(128)

typedef __bf16 bf16x8 __attribute__((ext_vector_type(8)));
typedef float f32x4 __attribute__((ext_vector_type(4)));

__device__ __forceinline__ ushort f2bf(float f) {
    unsigned u = __float_as_uint(f);
    u = (u + 0x7fffu + ((u >> 16) & 1u)) >> 16;
    return (ushort)u;
}
__device__ __forceinline__ float bfl(unsigned u) { return __uint_as_float(u << 16); }
__device__ __forceinline__ float bfh(unsigned u) { return __uint_as_float(u & 0xffff0000u); }

// ---------------------------------------------------------------------------
// K0: convert x (fp32) -> xb (bf16). 12.8M elements, 4 per thread.
// ---------------------------------------------------------------------------
__global__ __launch_bounds__(256) void k_prep(const float* __restrict__ x,
                                              ushort* __restrict__ xb) {
    int i = blockIdx.x * 256 + threadIdx.x;
    float4 v = *(const float4*)(x + (size_t)i * 4);
    ushort4 o = make_ushort4(f2bf(v.x), f2bf(v.y), f2bf(v.z), f2bf(v.w));
    *(ushort4*)(xb + (size_t)i * 4) = o;
}

// ---------------------------------------------------------------------------
// K1: build Wct (bf16, transposed [n][k], n in [0,384), k in [0,256)):
//   n <  128 : Wct[n][k] = W[k, n]                      (Wh part)
//   n >= 128 : part s/d, Wct[n][k] = sum_f W[k,h,f] * Wa[h, fb+f, c]
// One block per n.
// ---------------------------------------------------------------------------
__global__ __launch_bounds__(256) void k_combine(const float* __restrict__ W,
                                                 const float* __restrict__ Wa,
                                                 ushort* __restrict__ Wct) {
    __shared__ float col[64];
    const int n = blockIdx.x;
    const int t = threadIdx.x;
    if (n < 128) {
        Wct[(size_t)n * 256 + t] = f2bf(W[(size_t)t * NHF + n]);
        return;
    }
    const int part = (n - 128) >> 7;       // 0 = src-half, 1 = dst-half
    const int idx = (n - 128) & 127;
    const int h = idx >> 6;
    const int c = idx & 63;
    const int fb = part ? 64 : 0;
    if (t < 64) col[t] = Wa[(size_t)h * 8192 + (size_t)(fb + t) * 64 + c];
    __syncthreads();
    const float* wr = W + (size_t)t * NHF + h * 64;
    float acc = 0.f;
#pragma unroll
    for (int f = 0; f < 64; f++) acc += wr[f] * col[f];
    Wct[(size_t)n * 256 + t] = f2bf(acc);
}

// ---------------------------------------------------------------------------
// K2: Z[50000,384] = xb[50000,256] @ Wcomb  (bf16 MFMA 16x16x32, fp32 acc)
// Block tile 64(M) x 128(N), 4 waves (16 rows each), K-chunks of 32.
// A frag: lane holds A[m=lane&15][k=(lane>>4)*8+j]; D: row=(lane>>4)*4+r, col=lane&15.
// ---------------------------------------------------------------------------
#define LDT 40  // padded leading dim (bf16 elems) for LDS tiles
__global__ __launch_bounds__(256) void k_gemm(const ushort* __restrict__ xb,
                                              const ushort* __restrict__ Wct,
                                              ushort* __restrict__ Zb) {
    __shared__ ushort As[64 * LDT];    // 5120 B
    __shared__ ushort Bs[128 * LDT];   // 10240 B
    const int t = threadIdx.x;
    const int w = t >> 6, lane = t & 63;
    const int q = lane >> 4, r16 = lane & 15;
    const int row0 = blockIdx.x * 64;
    const int n0 = blockIdx.y * 128;

    f32x4 acc[8];
#pragma unroll
    for (int c = 0; c < 8; c++) acc[c] = (f32x4){0.f, 0.f, 0.f, 0.f};

    const int arow = t >> 2, aq = t & 3;
    const int agrow = row0 + arow;

    for (int k0 = 0; k0 < IN_DIM; k0 += 32) {
        uint4 av = make_uint4(0, 0, 0, 0);
        if (agrow < N_NODES)
            av = *(const uint4*)(xb + (size_t)agrow * IN_DIM + k0 + aq * 8);
        *(uint4*)(As + arow * LDT + aq * 8) = av;
#pragma unroll
        for (int i = 0; i < 2; i++) {
            int brow = (t >> 2) + 64 * i;
            uint4 bv = *(const uint4*)(Wct + (size_t)(n0 + brow) * 256 + k0 + aq * 8);
            *(uint4*)(Bs + brow * LDT + aq * 8) = bv;
        }
        __syncthreads();
        bf16x8 af = *(const bf16x8*)(As + (w * 16 + r16) * LDT + q * 8);
#pragma unroll
        for (int c = 0; c < 8; c++) {
            bf16x8 bf = *(const bf16x8*)(Bs + (c * 16 + r16) * LDT + q * 8);
            acc[c] = __builtin_amdgcn_mfma_f32_16x16x32_bf16(af, bf, acc[c], 0, 0, 0);
        }
        __syncthreads();
    }
#pragma unroll
    for (int c = 0; c < 8; c++) {
#pragma unroll
        for (int rr = 0; rr < 4; rr++) {
            int row = row0 + w * 16 + q * 4 + rr;
            if (row < N_NODES)
                Zb[(size_t)row * ZDIM + n0 + c * 16 + r16] = f2bf(acc[c][rr]);
        }
    }
}

// ---------------------------------------------------------------------------
// K3: seg[n] = lower_bound(dst, n); dst sorted.
// ---------------------------------------------------------------------------
__global__ void k_segstart(const int* __restrict__ dst, int* __restrict__ seg) {
    int n = blockIdx.x * blockDim.x + threadIdx.x;
    if (n > N_NODES) return;
    int lo = 0, hi = N_EDGES;
    while (lo < hi) {
        int mid = (lo + hi) >> 1;
        if (dst[mid] < n) lo = mid + 1; else hi = mid;
    }
    seg[n] = lo;
}

// ---------------------------------------------------------------------------
// K4: logits. 16-lane group per edge (4 edges/wave). Each lane loads 8 bf16
// (uint4) of Us[src] (Z cols 128..255) and Ud[dst] (Z cols 256..383), dots
// with a-vec, reduces in 3 xor-shuffle steps (lanes 0-7: head0, 8-15: head1).
// ---------------------------------------------------------------------------
__global__ __launch_bounds__(256) void k_logits(const ushort* __restrict__ Zb,
                                                const float* __restrict__ avec,
                                                const int* __restrict__ src,
                                                const int* __restrict__ dst,
                                                float* __restrict__ logits) {
    const int wv = (blockIdx.x * 256 + threadIdx.x) >> 6;
    const int lane = threadIdx.x & 63;
    const int g = lane >> 4, l16 = lane & 15;
    const int e = wv * 4 + g;
    if (e >= N_EDGES) return;
    const int s = src[e], d = dst[e];
    const float4 a0 = *(const float4*)(avec + l16 * 8);
    const float4 a1 = *(const float4*)(avec + l16 * 8 + 4);
    const uint4 us = *(const uint4*)(Zb + (size_t)s * ZDIM + 128 + l16 * 8);
    const uint4 ud = *(const uint4*)(Zb + (size_t)d * ZDIM + 256 + l16 * 8);
    float v, p = 0.f;
#define LR(vv) ((vv) > 0.f ? (vv) : ALPHA_SLOPE * (vv))
    v = bfl(us.x) + bfl(ud.x); p += LR(v) * a0.x;
    v = bfh(us.x) + bfh(ud.x); p += LR(v) * a0.y;
    v = bfl(us.y) + bfl(ud.y); p += LR(v) * a0.z;
    v = bfh(us.y) + bfh(ud.y); p += LR(v) * a0.w;
    v = bfl(us.z) + bfl(ud.z); p += LR(v) * a1.x;
    v = bfh(us.z) + bfh(ud.z); p += LR(v) * a1.y;
    v = bfl(us.w) + bfl(ud.w); p += LR(v) * a1.z;
    v = bfh(us.w) + bfh(ud.w); p += LR(v) * a1.w;
#undef LR
    p += __shfl_xor(p, 1, 64);
    p += __shfl_xor(p, 2, 64);
    p += __shfl_xor(p, 4, 64);
    if (l16 == 0) logits[(size_t)e * 2]     = p * (1.0f / TEMP);
    if (l16 == 8) logits[(size_t)e * 2 + 1] = p * (1.0f / TEMP);
}

// ---------------------------------------------------------------------------
// K5: per-(node,head) segment softmax (in-place logits -> alphas).
// ---------------------------------------------------------------------------
__global__ void k_softmax(const float* __restrict__ logits,
                          const int* __restrict__ seg,
                          float* __restrict__ alphas) {
    int t = blockIdx.x * blockDim.x + threadIdx.x;
    if (t >= N_NODES * 2) return;
    const int n = t >> 1;
    const int h = t & 1;
    const int e0 = seg[n], e1 = seg[n + 1];
    if (e0 >= e1) return;
    float m = -INFINITY;
    for (int e = e0; e < e1; e++) m = fmaxf(m, logits[(size_t)e * 2 + h]);
    float ssum = 0.f;
    for (int e = e0; e < e1; e++) ssum += expf(logits[(size_t)e * 2 + h] - m);
    const float inv = 1.f / (ssum + 1e-9f);
    for (int e = e0; e < e1; e++)
        alphas[(size_t)e * 2 + h] = expf(logits[(size_t)e * 2 + h] - m) * inv;
}

// ---------------------------------------------------------------------------
// K6: out[n,f] = 0.5*sum_h sum_e alpha[e,h]*Wh[src[e],h,f]. Wave per node;
// lane<32: head0 channels {2l,2l+1}; lane>=32: head1 same channels.
// One dword gather per lane per edge; xor-32 shuffle combines heads.
// ---------------------------------------------------------------------------
__global__ __launch_bounds__(256) void k_out(const ushort* __restrict__ Zb,
                                             const float* __restrict__ alphas,
                                             const int* __restrict__ src,
                                             const int* __restrict__ seg,
                                             float* __restrict__ out) {
    const int wv = threadIdx.x >> 6;
    const int lane = threadIdx.x & 63;
    const int n = blockIdx.x * 4 + wv;
    if (n >= N_NODES) return;
    const int e0 = seg[n], e1 = seg[n + 1];
    const int half = lane >> 5;
    float ax = 0.f, ay = 0.f;
    for (int e = e0; e < e1; e++) {
        const int s = src[e];
        const float al = alphas[(size_t)e * 2 + half];
        const unsigned wv2 = *(const unsigned*)(Zb + (size_t)s * ZDIM + 2 * lane);
        ax += al * bfl(wv2);
        ay += al * bfh(wv2);
    }
    ax += __shfl_xor(ax, 32, 64);
    ay += __shfl_xor(ay, 32, 64);
    if (lane < 32) {
        float2 o = make_float2(0.5f * ax, 0.5f * ay);
        *(float2*)(out + (size_t)n * 64 + 2 * lane) = o;
    }
}

// ---------------------------------------------------------------------------
extern "C" void kernel_launch(void* const* d_in, const int* in_sizes, int n_in,
                              void* d_out, int out_size, void* d_ws, size_t ws_size,
                              hipStream_t stream) {
    const float* x    = (const float*)d_in[0];
    const float* W    = (const float*)d_in[1];
    const float* Wa   = (const float*)d_in[2];
    const float* avec = (const float*)d_in[3];
    const int*   src  = (const int*)d_in[4];
    const int*   dst  = (const int*)d_in[5];
    float* out = (float*)d_out;

    ushort* xb  = (ushort*)d_ws;                              // 12,800,000 bf16 = 25.6 MB
    ushort* Zb  = xb + 12800000;                              // 19,200,000 bf16 = 38.4 MB
    ushort* Wct = Zb + 19200000;                              // 98,304 bf16
    float* logits = (float*)((char*)d_ws + 64196608);         // 800,000 fp32 (alphas in-place)
    int*   seg    = (int*)((char*)d_ws + 67396608);           // 50,001 ints

    k_prep    <<<12500, 256, 0, stream>>>(x, xb);
    k_combine <<<ZDIM, 256, 0, stream>>>(W, Wa, Wct);
    k_segstart<<<(N_NODES + 1 + 255) / 256, 256, 0, stream>>>(dst, seg);
    k_gemm    <<<dim3((N_NODES + 63) / 64, 3), 256, 0, stream>>>(xb, Wct, Zb);
    k_logits  <<<N_EDGES / 16, 256, 0, stream>>>(Zb, avec, src, dst, logits);
    k_softmax <<<(N_NODES * 2 + 255) / 256, 256, 0, stream>>>(logits, seg, logits);
    k_out     <<<(N_NODES + 3) / 4, 256, 0, stream>>>(Zb, logits, src, seg, out);
}

// Round 4
// 190.706 us; speedup vs baseline: 1.8428x; 1.1204x over previous
//
#include <hip/hip_runtime.h>
#include <hip/hip_bf16.h>
#include <math.h>

#define N_NODES 50000
#define N_EDGES 400000
#define IN_DIM 256
#define OUT_DIM 64
#define HEADS 2
#define ATTN_HIDDEN 64
#define ALPHA_SLOPE 0.2f
#define TEMP 0.55f
#define NHF 128   // HEADS*OUT_DIM
#define ZDIM 384  // Wh(128) | Us(128) | Ud(128)

typedef __bf16 bf16x8 __attribute__((ext_vector_type(8)));
typedef float f32x4 __attribute__((ext_vector_type(4)));

__device__ __forceinline__ ushort f2bf(float f) {
    unsigned u = __float_as_uint(f);
    u = (u + 0x7fffu + ((u >> 16) & 1u)) >> 16;
    return (ushort)u;
}
__device__ __forceinline__ unsigned pack2(float a, float b) {
    return (unsigned)f2bf(a) | ((unsigned)f2bf(b) << 16);
}
__device__ __forceinline__ float bfl(unsigned u) { return __uint_as_float(u << 16); }
__device__ __forceinline__ float bfh(unsigned u) { return __uint_as_float(u & 0xffff0000u); }

// ---------------------------------------------------------------------------
// K1: build Wct (bf16, [n][k], n in [0,384), k in [0,256)):
//   n <  128 : Wct[n][k] = W[k, n]
//   n >= 128 : Wct[n][k] = sum_f W[k,h,f] * Wa[h, fb+f, c]   (fb=0 src / 64 dst)
// ---------------------------------------------------------------------------
__global__ __launch_bounds__(256) void k_combine(const float* __restrict__ W,
                                                 const float* __restrict__ Wa,
                                                 ushort* __restrict__ Wct) {
    __shared__ float col[64];
    const int n = blockIdx.x;
    const int t = threadIdx.x;
    if (n < 128) {
        Wct[(size_t)n * 256 + t] = f2bf(W[(size_t)t * NHF + n]);
        return;
    }
    const int part = (n - 128) >> 7;       // 0 = src-half, 1 = dst-half
    const int idx = (n - 128) & 127;
    const int h = idx >> 6;
    const int c = idx & 63;
    const int fb = part ? 64 : 0;
    if (t < 64) col[t] = Wa[(size_t)h * 8192 + (size_t)(fb + t) * 64 + c];
    __syncthreads();
    const float* wr = W + (size_t)t * NHF + h * 64;
    float acc = 0.f;
#pragma unroll
    for (int f = 0; f < 64; f++) acc += wr[f] * col[f];
    Wct[(size_t)n * 256 + t] = f2bf(acc);
}

// ---------------------------------------------------------------------------
// K2: seg[n] = lower_bound(dst, n); dst sorted.
// ---------------------------------------------------------------------------
__global__ void k_segstart(const int* __restrict__ dst, int* __restrict__ seg) {
    int n = blockIdx.x * blockDim.x + threadIdx.x;
    if (n > N_NODES) return;
    int lo = 0, hi = N_EDGES;
    while (lo < hi) {
        int mid = (lo + hi) >> 1;
        if (dst[mid] < n) lo = mid + 1; else hi = mid;
    }
    seg[n] = lo;
}

// ---------------------------------------------------------------------------
// K3: Z[50000,384] = x[50000,256] @ Wcomb, fused fp32->bf16 convert on the
// A-staging path. Block tile 64(M) x 384(all N), 4 waves x 16 rows, K-chunk 32.
// 24 MFMAs per wave per chunk. A frag: A[m=lane&15][k=(lane>>4)*8+j];
// D: row=(lane>>4)*4+r, col=lane&15.
// ---------------------------------------------------------------------------
#define LDT 40  // padded leading dim (bf16 elems)
__global__ __launch_bounds__(256) void k_gemm(const float* __restrict__ x,
                                              const ushort* __restrict__ Wct,
                                              ushort* __restrict__ Zb) {
    __shared__ ushort As[64 * LDT];     //  5120 B
    __shared__ ushort Bs[384 * LDT];    // 30720 B
    const int t = threadIdx.x;
    const int w = t >> 6, lane = t & 63;
    const int q = lane >> 4, r16 = lane & 15;
    const int row0 = blockIdx.x * 64;

    f32x4 acc[24];
#pragma unroll
    for (int c = 0; c < 24; c++) acc[c] = (f32x4){0.f, 0.f, 0.f, 0.f};

    const int arow = t >> 2, a8 = (t & 3) * 8;
    const int agrow = row0 + arow;

    for (int k0 = 0; k0 < IN_DIM; k0 += 32) {
        // stage A: 64 rows x 32 k, convert fp32->bf16 in flight
        float4 v0 = make_float4(0.f, 0.f, 0.f, 0.f), v1 = v0;
        if (agrow < N_NODES) {
            const float* xp = x + (size_t)agrow * IN_DIM + k0 + a8;
            v0 = *(const float4*)xp;
            v1 = *(const float4*)(xp + 4);
        }
        uint4 av;
        av.x = pack2(v0.x, v0.y); av.y = pack2(v0.z, v0.w);
        av.z = pack2(v1.x, v1.y); av.w = pack2(v1.z, v1.w);
        *(uint4*)(As + arow * LDT + a8) = av;
        // stage B: 384 rows x 32 k
#pragma unroll
        for (int i = 0; i < 6; i++) {
            int brow = (t >> 2) + 64 * i;
            uint4 bv = *(const uint4*)(Wct + (size_t)brow * 256 + k0 + a8);
            *(uint4*)(Bs + brow * LDT + a8) = bv;
        }
        __syncthreads();
        bf16x8 af = *(const bf16x8*)(As + (w * 16 + r16) * LDT + q * 8);
#pragma unroll
        for (int c = 0; c < 24; c++) {
            bf16x8 bf = *(const bf16x8*)(Bs + (c * 16 + r16) * LDT + q * 8);
            acc[c] = __builtin_amdgcn_mfma_f32_16x16x32_bf16(af, bf, acc[c], 0, 0, 0);
        }
        __syncthreads();
    }
#pragma unroll
    for (int c = 0; c < 24; c++) {
#pragma unroll
        for (int rr = 0; rr < 4; rr++) {
            int row = row0 + w * 16 + q * 4 + rr;
            if (row < N_NODES)
                Zb[(size_t)row * ZDIM + c * 16 + r16] = f2bf(acc[c][rr]);
        }
    }
}

// ---------------------------------------------------------------------------
// K4: fused logits + online segment-softmax + weighted accumulate.
// Wave per node (4 nodes/block). Lane layout: h = lane>>5, cp = lane&31,
// lane owns channels {2cp, 2cp+1} of head h. Per edge: one dword gather of
// Us[src] + one of Wh[src]; Ud[dst] loaded once per node. Logit = 5-step
// xor-shuffle reduce within each 32-lane half (both heads in parallel).
// Online m/l/acc update; final cross-half combine via xor-32.
// ---------------------------------------------------------------------------
__global__ __launch_bounds__(256) void k_fused(const ushort* __restrict__ Zb,
                                               const float* __restrict__ avec,
                                               const int* __restrict__ src,
                                               const int* __restrict__ seg,
                                               float* __restrict__ out) {
    const int wv = threadIdx.x >> 6;
    const int lane = threadIdx.x & 63;
    const int n = blockIdx.x * 4 + wv;
    if (n >= N_NODES) return;
    const int h = lane >> 5, cp = lane & 31;
    const int choff = h * 64 + 2 * cp;    // channel offset within a 128-block

    const float2 a2 = *(const float2*)(avec + choff);
    const unsigned ud = *(const unsigned*)(Zb + (size_t)n * ZDIM + 256 + choff);
    const float udl = bfl(ud), udh = bfh(ud);

    const int e0 = seg[n], e1 = seg[n + 1];
    float m = -INFINITY, l = 0.f, acc0 = 0.f, acc1 = 0.f;

    unsigned us = 0, wh = 0;
    if (e0 < e1) {
        const int s = src[e0];
        us = *(const unsigned*)(Zb + (size_t)s * ZDIM + 128 + choff);
        wh = *(const unsigned*)(Zb + (size_t)s * ZDIM + choff);
    }
    for (int e = e0; e < e1; e++) {
        const unsigned cus = us, cwh = wh;
        if (e + 1 < e1) {                 // prefetch next edge during reduce
            const int sn = src[e + 1];
            us = *(const unsigned*)(Zb + (size_t)sn * ZDIM + 128 + choff);
            wh = *(const unsigned*)(Zb + (size_t)sn * ZDIM + choff);
        }
        float v0 = bfl(cus) + udl, v1 = bfh(cus) + udh;
        v0 = v0 > 0.f ? v0 : ALPHA_SLOPE * v0;
        v1 = v1 > 0.f ? v1 : ALPHA_SLOPE * v1;
        float p = v0 * a2.x + v1 * a2.y;
        p += __shfl_xor(p, 1, 64);
        p += __shfl_xor(p, 2, 64);
        p += __shfl_xor(p, 4, 64);
        p += __shfl_xor(p, 8, 64);
        p += __shfl_xor(p, 16, 64);
        const float logit = p * (1.0f / TEMP);
        const float nm = fmaxf(m, logit);
        const float sc = __expf(m - nm);       // first iter: exp(-inf)=0
        const float wgt = __expf(logit - nm);
        l = l * sc + wgt;
        acc0 = acc0 * sc + wgt * bfl(cwh);
        acc1 = acc1 * sc + wgt * bfh(cwh);
        m = nm;
    }
    const float inv = 1.f / (l + 1e-9f);       // matches ref: ex/(seg_sum+1e-9)
    float ax = acc0 * inv, ay = acc1 * inv;
    ax += __shfl_xor(ax, 32, 64);              // head0 + head1
    ay += __shfl_xor(ay, 32, 64);
    if (lane < 32) {
        float2 o = make_float2(0.5f * ax, 0.5f * ay);
        *(float2*)(out + (size_t)n * 64 + 2 * cp) = o;
    }
}

// ---------------------------------------------------------------------------
extern "C" void kernel_launch(void* const* d_in, const int* in_sizes, int n_in,
                              void* d_out, int out_size, void* d_ws, size_t ws_size,
                              hipStream_t stream) {
    const float* x    = (const float*)d_in[0];
    const float* W    = (const float*)d_in[1];
    const float* Wa   = (const float*)d_in[2];
    const float* avec = (const float*)d_in[3];
    const int*   src  = (const int*)d_in[4];
    const int*   dst  = (const int*)d_in[5];
    float* out = (float*)d_out;

    ushort* Zb  = (ushort*)d_ws;                       // 19,200,000 bf16 = 38.4 MB
    ushort* Wct = Zb + 19200000;                       // 98,304 bf16
    int*    seg = (int*)((char*)d_ws + 38596608);      // 50,001 ints

    k_combine <<<ZDIM, 256, 0, stream>>>(W, Wa, Wct);
    k_segstart<<<(N_NODES + 1 + 255) / 256, 256, 0, stream>>>(dst, seg);
    k_gemm    <<<(N_NODES + 63) / 64, 256, 0, stream>>>(x, Wct, Zb);
    k_fused   <<<(N_NODES + 3) / 4, 256, 0, stream>>>(Zb, avec, src, seg, out);
}

// Round 5
// 169.123 us; speedup vs baseline: 2.0780x; 1.1276x over previous
//
#include <hip/hip_runtime.h>
#include <hip/hip_bf16.h>
#include <math.h>

#define N_NODES 50000
#define N_EDGES 400000
#define IN_DIM 256
#define OUT_DIM 64
#define HEADS 2
#define ATTN_HIDDEN 64
#define ALPHA_SLOPE 0.2f
#define TEMP 0.55f
#define NHF 128   // HEADS*OUT_DIM
#define ZDIM 384  // Wh(128) | Us(128) | Ud(128)

typedef __bf16 bf16x8 __attribute__((ext_vector_type(8)));
typedef float f32x4 __attribute__((ext_vector_type(4)));

__device__ __forceinline__ ushort f2bf(float f) {
    unsigned u = __float_as_uint(f);
    u = (u + 0x7fffu + ((u >> 16) & 1u)) >> 16;
    return (ushort)u;
}
__device__ __forceinline__ unsigned pack2(float a, float b) {
    return (unsigned)f2bf(a) | ((unsigned)f2bf(b) << 16);
}
__device__ __forceinline__ float bfl(unsigned u) { return __uint_as_float(u << 16); }
__device__ __forceinline__ float bfh(unsigned u) { return __uint_as_float(u & 0xffff0000u); }

// ---------------------------------------------------------------------------
// K1: build Wct (bf16, [n][k], n in [0,384), k in [0,256)):
//   n <  128 : Wct[n][k] = W[k, n]
//   n >= 128 : Wct[n][k] = sum_f W[k,h,f] * Wa[h, fb+f, c]   (fb=0 src / 64 dst)
// ---------------------------------------------------------------------------
__global__ __launch_bounds__(256) void k_combine(const float* __restrict__ W,
                                                 const float* __restrict__ Wa,
                                                 ushort* __restrict__ Wct) {
    __shared__ float col[64];
    const int n = blockIdx.x;
    const int t = threadIdx.x;
    if (n < 128) {
        Wct[(size_t)n * 256 + t] = f2bf(W[(size_t)t * NHF + n]);
        return;
    }
    const int part = (n - 128) >> 7;       // 0 = src-half, 1 = dst-half
    const int idx = (n - 128) & 127;
    const int h = idx >> 6;
    const int c = idx & 63;
    const int fb = part ? 64 : 0;
    if (t < 64) col[t] = Wa[(size_t)h * 8192 + (size_t)(fb + t) * 64 + c];
    __syncthreads();
    const float* wr = W + (size_t)t * NHF + h * 64;
    float acc = 0.f;
#pragma unroll
    for (int f = 0; f < 64; f++) acc += wr[f] * col[f];
    Wct[(size_t)n * 256 + t] = f2bf(acc);
}

// ---------------------------------------------------------------------------
// K2: seg[n] = lower_bound(dst, n); dst sorted.
// ---------------------------------------------------------------------------
__global__ void k_segstart(const int* __restrict__ dst, int* __restrict__ seg) {
    int n = blockIdx.x * blockDim.x + threadIdx.x;
    if (n > N_NODES) return;
    int lo = 0, hi = N_EDGES;
    while (lo < hi) {
        int mid = (lo + hi) >> 1;
        if (dst[mid] < n) lo = mid + 1; else hi = mid;
    }
    seg[n] = lo;
}

// ---------------------------------------------------------------------------
// K3: Z[50000,384] = x[50000,256] @ Wcomb, fused fp32->bf16 convert on the
// A-staging path. Block tile 64(M) x 384(all N), 4 waves x 16 rows, K-chunk 32.
// ---------------------------------------------------------------------------
#define LDT 40  // padded leading dim (bf16 elems)
__global__ __launch_bounds__(256) void k_gemm(const float* __restrict__ x,
                                              const ushort* __restrict__ Wct,
                                              ushort* __restrict__ Zb) {
    __shared__ ushort As[64 * LDT];     //  5120 B
    __shared__ ushort Bs[384 * LDT];    // 30720 B
    const int t = threadIdx.x;
    const int w = t >> 6, lane = t & 63;
    const int q = lane >> 4, r16 = lane & 15;
    const int row0 = blockIdx.x * 64;

    f32x4 acc[24];
#pragma unroll
    for (int c = 0; c < 24; c++) acc[c] = (f32x4){0.f, 0.f, 0.f, 0.f};

    const int arow = t >> 2, a8 = (t & 3) * 8;
    const int agrow = row0 + arow;

    for (int k0 = 0; k0 < IN_DIM; k0 += 32) {
        float4 v0 = make_float4(0.f, 0.f, 0.f, 0.f), v1 = v0;
        if (agrow < N_NODES) {
            const float* xp = x + (size_t)agrow * IN_DIM + k0 + a8;
            v0 = *(const float4*)xp;
            v1 = *(const float4*)(xp + 4);
        }
        uint4 av;
        av.x = pack2(v0.x, v0.y); av.y = pack2(v0.z, v0.w);
        av.z = pack2(v1.x, v1.y); av.w = pack2(v1.z, v1.w);
        *(uint4*)(As + arow * LDT + a8) = av;
#pragma unroll
        for (int i = 0; i < 6; i++) {
            int brow = (t >> 2) + 64 * i;
            uint4 bv = *(const uint4*)(Wct + (size_t)brow * 256 + k0 + a8);
            *(uint4*)(Bs + brow * LDT + a8) = bv;
        }
        __syncthreads();
        bf16x8 af = *(const bf16x8*)(As + (w * 16 + r16) * LDT + q * 8);
#pragma unroll
        for (int c = 0; c < 24; c++) {
            bf16x8 bf = *(const bf16x8*)(Bs + (c * 16 + r16) * LDT + q * 8);
            acc[c] = __builtin_amdgcn_mfma_f32_16x16x32_bf16(af, bf, acc[c], 0, 0, 0);
        }
        __syncthreads();
    }
#pragma unroll
    for (int c = 0; c < 24; c++) {
#pragma unroll
        for (int rr = 0; rr < 4; rr++) {
            int row = row0 + w * 16 + q * 4 + rr;
            if (row < N_NODES)
                Zb[(size_t)row * ZDIM + c * 16 + r16] = f2bf(acc[c][rr]);
        }
    }
}

// ---------------------------------------------------------------------------
// K4: fused logits + online segment-softmax + weighted accumulate.
// 16 lanes per node, 4 nodes per wave, 16 nodes per block (50000 = 3125*16).
// Lane l16 owns channels 8*l16..8*l16+7 of the 128-channel block (l16<8:
// head0, l16>=8: head1). Per edge: uint4 gather of Us[src] + Wh[src];
// logit reduce = 3 xor-shuffles within the group's 8-lane head halves;
// per-lane (m,l) tracks the lane's own head. 4 independent edge chains per
// wave hide gather/shuffle/exp latency. Head-mean via final xor-8 shuffle.
// ---------------------------------------------------------------------------
__global__ __launch_bounds__(256) void k_fused(const ushort* __restrict__ Zb,
                                               const float* __restrict__ avec,
                                               const int* __restrict__ src,
                                               const int* __restrict__ seg,
                                               float* __restrict__ out) {
    const int lane = threadIdx.x & 63;
    const int wv = threadIdx.x >> 6;
    const int g = lane >> 4, l16 = lane & 15;
    const int n = blockIdx.x * 16 + wv * 4 + g;
    if (n >= N_NODES) return;
    const int choff = 8 * l16;

    const float4 af0 = *(const float4*)(avec + choff);
    const float4 af1 = *(const float4*)(avec + choff + 4);
    const float a[8] = {af0.x, af0.y, af0.z, af0.w, af1.x, af1.y, af1.z, af1.w};

    const uint4 udv = *(const uint4*)(Zb + (size_t)n * ZDIM + 256 + choff);
    const float ud[8] = {bfl(udv.x), bfh(udv.x), bfl(udv.y), bfh(udv.y),
                         bfl(udv.z), bfh(udv.z), bfl(udv.w), bfh(udv.w)};

    const int e0 = seg[n], e1 = seg[n + 1];
    float m = -INFINITY, l = 0.f;
    float acc[8] = {0.f, 0.f, 0.f, 0.f, 0.f, 0.f, 0.f, 0.f};

    uint4 us = make_uint4(0, 0, 0, 0), wh = us;
    if (e0 < e1) {
        const int s = src[e0];
        us = *(const uint4*)(Zb + (size_t)s * ZDIM + 128 + choff);
        wh = *(const uint4*)(Zb + (size_t)s * ZDIM + choff);
    }
    for (int e = e0; e < e1; e++) {
        const uint4 cus = us, cwh = wh;
        if (e + 1 < e1) {                 // prefetch next edge during reduce
            const int sn = src[e + 1];
            us = *(const uint4*)(Zb + (size_t)sn * ZDIM + 128 + choff);
            wh = *(const uint4*)(Zb + (size_t)sn * ZDIM + choff);
        }
        // 8-channel partial dot with lrelu(v)=max(v, 0.2v)
        float p;
        {
            float v0, v1, s0, s1;
            v0 = bfl(cus.x) + ud[0]; v1 = bfh(cus.x) + ud[1];
            s0 = fmaxf(v0, ALPHA_SLOPE * v0); s1 = fmaxf(v1, ALPHA_SLOPE * v1);
            p = s0 * a[0] + s1 * a[1];
            v0 = bfl(cus.y) + ud[2]; v1 = bfh(cus.y) + ud[3];
            s0 = fmaxf(v0, ALPHA_SLOPE * v0); s1 = fmaxf(v1, ALPHA_SLOPE * v1);
            p += s0 * a[2] + s1 * a[3];
            v0 = bfl(cus.z) + ud[4]; v1 = bfh(cus.z) + ud[5];
            s0 = fmaxf(v0, ALPHA_SLOPE * v0); s1 = fmaxf(v1, ALPHA_SLOPE * v1);
            p += s0 * a[4] + s1 * a[5];
            v0 = bfl(cus.w) + ud[6]; v1 = bfh(cus.w) + ud[7];
            s0 = fmaxf(v0, ALPHA_SLOPE * v0); s1 = fmaxf(v1, ALPHA_SLOPE * v1);
            p += s0 * a[6] + s1 * a[7];
        }
        p += __shfl_xor(p, 1, 64);
        p += __shfl_xor(p, 2, 64);
        p += __shfl_xor(p, 4, 64);        // lanes 0-7: head0 logit, 8-15: head1
        const float logit = p * (1.0f / TEMP);
        const float nm = fmaxf(m, logit);
        const float sc = __expf(m - nm);       // first iter: exp(-inf)=0
        const float wgt = __expf(logit - nm);
        l = l * sc + wgt;
        acc[0] = acc[0] * sc + wgt * bfl(cwh.x);
        acc[1] = acc[1] * sc + wgt * bfh(cwh.x);
        acc[2] = acc[2] * sc + wgt * bfl(cwh.y);
        acc[3] = acc[3] * sc + wgt * bfh(cwh.y);
        acc[4] = acc[4] * sc + wgt * bfl(cwh.z);
        acc[5] = acc[5] * sc + wgt * bfh(cwh.z);
        acc[6] = acc[6] * sc + wgt * bfl(cwh.w);
        acc[7] = acc[7] * sc + wgt * bfh(cwh.w);
        m = nm;
    }
    const float inv = 0.5f / (l + 1e-9f);      // matches ref + head-mean 0.5
#pragma unroll
    for (int j = 0; j < 8; j++) {
        const float v = acc[j] * inv;
        acc[j] = v + __shfl_xor(v, 8, 64);     // head0[c] + head1[c]
    }
    if (l16 < 8) {
        float4 o0 = make_float4(acc[0], acc[1], acc[2], acc[3]);
        float4 o1 = make_float4(acc[4], acc[5], acc[6], acc[7]);
        float* op = out + (size_t)n * 64 + choff;
        *(float4*)op = o0;
        *(float4*)(op + 4) = o1;
    }
}

// ---------------------------------------------------------------------------
extern "C" void kernel_launch(void* const* d_in, const int* in_sizes, int n_in,
                              void* d_out, int out_size, void* d_ws, size_t ws_size,
                              hipStream_t stream) {
    const float* x    = (const float*)d_in[0];
    const float* W    = (const float*)d_in[1];
    const float* Wa   = (const float*)d_in[2];
    const float* avec = (const float*)d_in[3];
    const int*   src  = (const int*)d_in[4];
    const int*   dst  = (const int*)d_in[5];
    float* out = (float*)d_out;

    ushort* Zb  = (ushort*)d_ws;                       // 19,200,000 bf16 = 38.4 MB
    ushort* Wct = Zb + 19200000;                       // 98,304 bf16
    int*    seg = (int*)((char*)d_ws + 38596608);      // 50,001 ints

    k_combine <<<ZDIM, 256, 0, stream>>>(W, Wa, Wct);
    k_segstart<<<(N_NODES + 1 + 255) / 256, 256, 0, stream>>>(dst, seg);
    k_gemm    <<<(N_NODES + 63) / 64, 256, 0, stream>>>(x, Wct, Zb);
    k_fused   <<<(N_NODES + 15) / 16, 256, 0, stream>>>(Zb, avec, src, seg, out);
}